// Round 6
// baseline (126.936 us; speedup 1.0000x reference)
//
#include <hip/hip_runtime.h>

// B=16384, DIM=64, 8 coupling steps, H=8, D2=32.
// y = J^{-1} g applied analytically (triangular coupling blocks -> MLP JVPs);
// intermediate states recovered by inverting the flow from z = phi(x).
//
// Mapping: 8 lanes / element. q = tid&3 owns dims {q*8..q*8+7} of each
// 32-vector; hb = (tid>>2)&1 selects t-net / s-net (results exchanged via
// ds_swizzle xor-4). Within a quad each lane computes FULL rows {q, q+4} of
// every MLP layer (zero FMA redundancy). Weights are packed f16x2 in LDS,
// consumed with v_dot2_f32_f16 (fp32 accumulate).
// R6: layer-1/2 dot chains split into independent partial accumulators
// (4-deep) to raise ILP — R5 showed VALUBusy 44% from 16-deep serial chains.

namespace {

typedef _Float16 f16;
typedef f16 f16x2 __attribute__((ext_vector_type(2)));

constexpr int NB    = 16384;
constexpr int NSTEP = 8;

__device__ __forceinline__ float frcp(float x) { return __builtin_amdgcn_rcpf(x); }

__device__ __forceinline__ float ftanh(float x) {
  float e = __expf(2.f * x);
  return 1.f - 2.f * frcp(e + 1.f);
}

__device__ __forceinline__ float fdot2(f16x2 a, f16x2 b, float c) {
  return __builtin_amdgcn_fdot2(a, b, c, false);
}
__device__ __forceinline__ f16x2 pk(float a, float b) {
  auto r = __builtin_amdgcn_cvt_pkrtz(a, b);
  return __builtin_bit_cast(f16x2, r);
}
template <int C>
__device__ __forceinline__ f16x2 dpp_h2(f16x2 v) {
  int r = __builtin_amdgcn_update_dpp(0, __builtin_bit_cast(int, v), C, 0xF, 0xF, true);
  return __builtin_bit_cast(f16x2, r);
}
// lane l <-> l^4 exchange (t/s across the two quads of an element)
__device__ __forceinline__ float swz_x4(float v) {
  return __int_as_float(__builtin_amdgcn_ds_swizzle(__float_as_int(v), 0x101F));
}
__device__ __forceinline__ void ld4h(const f16x2* p, f16x2& a, f16x2& b,
                                     f16x2& c, f16x2& d) {
  float4 w = *(const float4*)p;  // one ds_read_b128
  a = __builtin_bit_cast(f16x2, w.x);
  b = __builtin_bit_cast(f16x2, w.y);
  c = __builtin_bit_cast(f16x2, w.z);
  d = __builtin_bit_cast(f16x2, w.w);
}

// Apply one MLP (net m) and optionally its JVP, rows {q,q+4} per lane.
// hW0: [m][j(8)][16 pairs k]; hW1: [m][j(8)][4 pairs (p,p+4)];
// hW2: [m][r(8)][q(4)][4 pairs (p,p+4)] for out dim d=q*8+r; biases fp32.
template <bool JVP>
__device__ __forceinline__ void net_apply(
    const f16x2* __restrict__ hW0, const f16x2* __restrict__ hW1,
    const f16x2* __restrict__ hW2, const float* __restrict__ sB0,
    const float* __restrict__ sB1, const float* __restrict__ sB2,
    int m, int q, const float v8[8], const float* __restrict__ u8,
    float out8[8], float* __restrict__ jout8) {
  // pack own chunk, rotate to gather the full 32-dim vector
  f16x2 V[4][4], U[4][4];
#pragma unroll
  for (int p = 0; p < 4; ++p) V[0][p] = pk(v8[2 * p], v8[2 * p + 1]);
#pragma unroll
  for (int p = 0; p < 4; ++p) {
    V[1][p] = dpp_h2<0x39>(V[0][p]);  // chunk (q+1)&3
    V[2][p] = dpp_h2<0x4E>(V[0][p]);  // chunk (q+2)&3
    V[3][p] = dpp_h2<0x93>(V[0][p]);  // chunk (q+3)&3
  }
  if constexpr (JVP) {
#pragma unroll
    for (int p = 0; p < 4; ++p) U[0][p] = pk(u8[2 * p], u8[2 * p + 1]);
#pragma unroll
    for (int p = 0; p < 4; ++p) {
      U[1][p] = dpp_h2<0x39>(U[0][p]);
      U[2][p] = dpp_h2<0x4E>(U[0][p]);
      U[3][p] = dpp_h2<0x93>(U[0][p]);
    }
  }

  // ---- layer 1: rows q and q+4; per-r partial accumulators (ILP) ----
  const f16x2* W0m = hW0 + m * 128;
  float sva[4], svb[4], sua[4], sub[4];
#pragma unroll
  for (int r = 0; r < 4; ++r) {
    const int c = (q + r) & 3;
    f16x2 a0, a1, a2, a3, b0, b1, b2, b3;
    ld4h(W0m + q * 16 + c * 4, a0, a1, a2, a3);
    ld4h(W0m + (q + 4) * 16 + c * 4, b0, b1, b2, b3);
    float s0 = fdot2(a0, V[r][0], 0.f);
    s0 = fdot2(a1, V[r][1], s0);
    s0 = fdot2(a2, V[r][2], s0);
    s0 = fdot2(a3, V[r][3], s0);
    sva[r] = s0;
    float s1 = fdot2(b0, V[r][0], 0.f);
    s1 = fdot2(b1, V[r][1], s1);
    s1 = fdot2(b2, V[r][2], s1);
    s1 = fdot2(b3, V[r][3], s1);
    svb[r] = s1;
    if constexpr (JVP) {
      float s2 = fdot2(a0, U[r][0], 0.f);
      s2 = fdot2(a1, U[r][1], s2);
      s2 = fdot2(a2, U[r][2], s2);
      s2 = fdot2(a3, U[r][3], s2);
      sua[r] = s2;
      float s3 = fdot2(b0, U[r][0], 0.f);
      s3 = fdot2(b1, U[r][1], s3);
      s3 = fdot2(b2, U[r][2], s3);
      s3 = fdot2(b3, U[r][3], s3);
      sub[r] = s3;
    }
  }
  const float svA = (sva[0] + sva[1]) + (sva[2] + sva[3]);
  const float svB = (svb[0] + svb[1]) + (svb[2] + svb[3]);
  const float h1a = ftanh(svA + sB0[m * 8 + q]);
  const float h1b = ftanh(svB + sB0[m * 8 + q + 4]);
  const f16x2 h1p = pk(h1a, h1b);  // pair (h1[q], h1[q+4])
  f16x2 H1[4] = {dpp_h2<0x00>(h1p), dpp_h2<0x55>(h1p), dpp_h2<0xAA>(h1p),
                 dpp_h2<0xFF>(h1p)};
  f16x2 G1[4];
  if constexpr (JVP) {
    const float suA = (sua[0] + sua[1]) + (sua[2] + sua[3]);
    const float suB = (sub[0] + sub[1]) + (sub[2] + sub[3]);
    const float g1a = (1.f - h1a * h1a) * suA;
    const float g1b = (1.f - h1b * h1b) * suB;
    const f16x2 g1p = pk(g1a, g1b);
    G1[0] = dpp_h2<0x00>(g1p); G1[1] = dpp_h2<0x55>(g1p);
    G1[2] = dpp_h2<0xAA>(g1p); G1[3] = dpp_h2<0xFF>(g1p);
  }

  // ---- layer 2: rows q and q+4 (two partial chains each) ----
  f16x2 wa0, wa1, wa2, wa3, wb0, wb1, wb2, wb3;
  ld4h(hW1 + m * 32 + q * 4, wa0, wa1, wa2, wa3);
  ld4h(hW1 + m * 32 + q * 4 + 16, wb0, wb1, wb2, wb3);
  float t2a0 = fdot2(wa0, H1[0], sB1[m * 8 + q]);
  t2a0 = fdot2(wa1, H1[1], t2a0);
  float t2a1 = fdot2(wa2, H1[2], 0.f);
  t2a1 = fdot2(wa3, H1[3], t2a1);
  float t2b0 = fdot2(wb0, H1[0], sB1[m * 8 + q + 4]);
  t2b0 = fdot2(wb1, H1[1], t2b0);
  float t2b1 = fdot2(wb2, H1[2], 0.f);
  t2b1 = fdot2(wb3, H1[3], t2b1);
  const float h2a = ftanh(t2a0 + t2a1);
  const float h2b = ftanh(t2b0 + t2b1);
  const f16x2 h2p = pk(h2a, h2b);
  f16x2 H2[4] = {dpp_h2<0x00>(h2p), dpp_h2<0x55>(h2p), dpp_h2<0xAA>(h2p),
                 dpp_h2<0xFF>(h2p)};
  f16x2 G2[4];
  if constexpr (JVP) {
    float ga0 = fdot2(wa0, G1[0], 0.f);
    ga0 = fdot2(wa1, G1[1], ga0);
    float ga1 = fdot2(wa2, G1[2], 0.f);
    ga1 = fdot2(wa3, G1[3], ga1);
    float gb0 = fdot2(wb0, G1[0], 0.f);
    gb0 = fdot2(wb1, G1[1], gb0);
    float gb1 = fdot2(wb2, G1[2], 0.f);
    gb1 = fdot2(wb3, G1[3], gb1);
    const float g2a = (1.f - h2a * h2a) * (ga0 + ga1);
    const float g2b = (1.f - h2b * h2b) * (gb0 + gb1);
    const f16x2 g2p = pk(g2a, g2b);
    G2[0] = dpp_h2<0x00>(g2p); G2[1] = dpp_h2<0x55>(g2p);
    G2[2] = dpp_h2<0xAA>(g2p); G2[3] = dpp_h2<0xFF>(g2p);
  }

  // ---- layer 3: out dims d = q*8 + r (8/16 independent chains) ----
  const f16x2* W2m = hW2 + m * 128 + q * 4;
  const float4* b2v = (const float4*)(sB2 + m * 32 + q * 8);
  const float4 bl = b2v[0], bh = b2v[1];
  const float bb[8] = {bl.x, bl.y, bl.z, bl.w, bh.x, bh.y, bh.z, bh.w};
#pragma unroll
  for (int r = 0; r < 8; ++r) {
    f16x2 c0, c1, c2, c3;
    ld4h(W2m + r * 16, c0, c1, c2, c3);
    float o0 = fdot2(c0, H2[0], bb[r]);
    o0 = fdot2(c1, H2[1], o0);
    float o1 = fdot2(c2, H2[2], 0.f);
    o1 = fdot2(c3, H2[3], o1);
    out8[r] = o0 + o1;
    if constexpr (JVP) {
      float j0 = fdot2(c0, G2[0], 0.f);
      j0 = fdot2(c1, G2[1], j0);
      float j1 = fdot2(c2, G2[2], 0.f);
      j1 = fdot2(c3, G2[3], j1);
      jout8[r] = j0 + j1;
    }
  }
}

}  // namespace

// 256 threads = 32 elements/block, grid 512 -> 2048 waves = 2/SIMD.
__global__ __launch_bounds__(256, 2) void nf_policy_kernel(
    const float* __restrict__ x, const float* __restrict__ xs,
    const float* __restrict__ gW0, const float* __restrict__ gb0,
    const float* __restrict__ gW1, const float* __restrict__ gb1,
    const float* __restrict__ gW2, const float* __restrict__ gb2,
    float* __restrict__ out) {
  __shared__ __align__(16) f16x2 hW0[4096];  // [32m][8j][16 k-pairs]
  __shared__ __align__(16) f16x2 hW1[1024];  // [32m][8j][4 (p,p+4)-pairs]
  __shared__ __align__(16) f16x2 hW2[4096];  // [32m][8r][4q][4 (p,p+4)-pairs]
  __shared__ __align__(16) float sB0[256];   // [32m][8]
  __shared__ __align__(16) float sB1[256];   // [32m][8]
  __shared__ __align__(16) float sB2[1024];  // [32m][32]

  const int tid = threadIdx.x;
  // ---- stage weights (fp32 global -> f16x2 LDS) ----
  for (int t = tid; t < 4096; t += 256)
    hW0[t] = pk(gW0[2 * t], gW0[2 * t + 1]);
  for (int t = tid; t < 1024; t += 256) {
    const int m = t >> 5, j = (t >> 2) & 7, p = t & 3;
    const float* base = gW1 + m * 64 + j * 8 + p;
    hW1[t] = pk(base[0], base[4]);
  }
  for (int t = tid; t < 4096; t += 256) {
    const int m = t >> 7, r = (t >> 4) & 7, qq = (t >> 2) & 3, p = t & 3;
    const float* base = gW2 + m * 256 + (qq * 8 + r) * 8 + p;
    hW2[t] = pk(base[0], base[4]);
  }
  for (int t = tid; t < 256; t += 256) {
    sB0[t] = gb0[t];
    sB1[t] = gb1[t];
  }
  for (int t = tid; t < 1024; t += 256) sB2[t] = gb2[t];
  __syncthreads();

  const int e = blockIdx.x * 32 + (tid >> 3);
  const int q = tid & 3;
  const bool hb = (tid >> 2) & 1;  // 0: t-net, 1: s-net

  float lo8[8], up8[8], av8[8], bv8[8];
  {
    const float4* xl = (const float4*)(x + (size_t)e * 64 + q * 8);
    const float4* xu = (const float4*)(x + (size_t)e * 64 + 32 + q * 8);
    const float4* sl = (const float4*)(xs + (size_t)e * 64 + q * 8);
    const float4* su = (const float4*)(xs + (size_t)e * 64 + 32 + q * 8);
    float4 a, c;
    a = xl[0]; c = sl[0];
    lo8[0] = a.x; lo8[1] = a.y; lo8[2] = a.z; lo8[3] = a.w;
    av8[0] = -2.f * (a.x - c.x); av8[1] = -2.f * (a.y - c.y);
    av8[2] = -2.f * (a.z - c.z); av8[3] = -2.f * (a.w - c.w);
    a = xl[1]; c = sl[1];
    lo8[4] = a.x; lo8[5] = a.y; lo8[6] = a.z; lo8[7] = a.w;
    av8[4] = -2.f * (a.x - c.x); av8[5] = -2.f * (a.y - c.y);
    av8[6] = -2.f * (a.z - c.z); av8[7] = -2.f * (a.w - c.w);
    a = xu[0]; c = su[0];
    up8[0] = a.x; up8[1] = a.y; up8[2] = a.z; up8[3] = a.w;
    bv8[0] = -2.f * (a.x - c.x); bv8[1] = -2.f * (a.y - c.y);
    bv8[2] = -2.f * (a.z - c.z); bv8[3] = -2.f * (a.w - c.w);
    a = xu[1]; c = su[1];
    up8[4] = a.x; up8[5] = a.y; up8[6] = a.z; up8[7] = a.w;
    bv8[4] = -2.f * (a.x - c.x); bv8[5] = -2.f * (a.y - c.y);
    bv8[6] = -2.f * (a.z - c.z); bv8[7] = -2.f * (a.w - c.w);
  }

  float r8[8], jr8[8], t8[8], s8[8], ut8[8], us8[8];

  // ---------------- forward: z = phi(x) ----------------
#pragma unroll 1
  for (int i = 0; i < NSTEP; ++i) {
    {
      const int m = i * 4 + (int)hb;  // t1 / s1
      net_apply<false>(hW0, hW1, hW2, sB0, sB1, sB2, m, q, lo8, nullptr, r8,
                       nullptr);
#pragma unroll
      for (int k = 0; k < 8; ++k) {
        float o = swz_x4(r8[k]);
        t8[k] = hb ? o : r8[k];
        s8[k] = hb ? r8[k] : o;
      }
#pragma unroll
      for (int k = 0; k < 8; ++k) up8[k] = fmaf(up8[k], __expf(s8[k]), t8[k]);
    }
    {
      const int m = i * 4 + 2 + (int)hb;  // t2 / s2
      net_apply<false>(hW0, hW1, hW2, sB0, sB1, sB2, m, q, up8, nullptr, r8,
                       nullptr);
#pragma unroll
      for (int k = 0; k < 8; ++k) {
        float o = swz_x4(r8[k]);
        t8[k] = hb ? o : r8[k];
        s8[k] = hb ? r8[k] : o;
      }
#pragma unroll
      for (int k = 0; k < 8; ++k) lo8[k] = fmaf(lo8[k], __expf(s8[k]), t8[k]);
    }
  }

  // ------------- backward: y = J^{-1} g, inverting the flow -------------
#pragma unroll 1
  for (int i = NSTEP - 1; i >= 0; --i) {
    {  // T2^{-1}: eval t2/s2 at up', JVP at bv
      const int m = i * 4 + 2 + (int)hb;
      net_apply<true>(hW0, hW1, hW2, sB0, sB1, sB2, m, q, up8, bv8, r8, jr8);
#pragma unroll
      for (int k = 0; k < 8; ++k) {
        float o = swz_x4(r8[k]);
        t8[k] = hb ? o : r8[k];
        s8[k] = hb ? r8[k] : o;
        float ou = swz_x4(jr8[k]);
        ut8[k] = hb ? ou : jr8[k];
        us8[k] = hb ? jr8[k] : ou;
      }
#pragma unroll
      for (int k = 0; k < 8; ++k) {
        const float es = __expf(s8[k]);
        const float esi = __expf(-s8[k]);
        lo8[k] = (lo8[k] - t8[k]) * esi;  // pre-step lo
        av8[k] = (av8[k] - ut8[k] - lo8[k] * es * us8[k]) * esi;
      }
    }
    {  // T1^{-1}: eval t1/s1 at lo (pre-step), JVP at av (updated)
      const int m = i * 4 + (int)hb;
      net_apply<true>(hW0, hW1, hW2, sB0, sB1, sB2, m, q, lo8, av8, r8, jr8);
#pragma unroll
      for (int k = 0; k < 8; ++k) {
        float o = swz_x4(r8[k]);
        t8[k] = hb ? o : r8[k];
        s8[k] = hb ? r8[k] : o;
        float ou = swz_x4(jr8[k]);
        ut8[k] = hb ? ou : jr8[k];
        us8[k] = hb ? jr8[k] : ou;
      }
#pragma unroll
      for (int k = 0; k < 8; ++k) {
        const float es = __expf(s8[k]);
        const float esi = __expf(-s8[k]);
        up8[k] = (up8[k] - t8[k]) * esi;  // pre-step up
        bv8[k] = (bv8[k] - ut8[k] - up8[k] * es * us8[k]) * esi;
      }
    }
  }

  if (!hb) {
    float4* ol = (float4*)(out + (size_t)e * 64 + q * 8);
    float4* ou = (float4*)(out + (size_t)e * 64 + 32 + q * 8);
    float4 v;
    v.x = av8[0]; v.y = av8[1]; v.z = av8[2]; v.w = av8[3]; ol[0] = v;
    v.x = av8[4]; v.y = av8[5]; v.z = av8[6]; v.w = av8[7]; ol[1] = v;
    v.x = bv8[0]; v.y = bv8[1]; v.z = bv8[2]; v.w = bv8[3]; ou[0] = v;
    v.x = bv8[4]; v.y = bv8[5]; v.z = bv8[6]; v.w = bv8[7]; ou[1] = v;
  }
}

extern "C" void kernel_launch(void* const* d_in, const int* in_sizes, int n_in,
                              void* d_out, int out_size, void* d_ws,
                              size_t ws_size, hipStream_t stream) {
  const float* x  = (const float*)d_in[0];
  const float* xs = (const float*)d_in[1];
  const float* W0 = (const float*)d_in[2];
  const float* b0 = (const float*)d_in[3];
  const float* W1 = (const float*)d_in[4];
  const float* b1 = (const float*)d_in[5];
  const float* W2 = (const float*)d_in[6];
  const float* b2 = (const float*)d_in[7];
  float* out = (float*)d_out;

  dim3 grid(NB * 8 / 256);  // 512 blocks, 32 elements each
  dim3 block(256);
  nf_policy_kernel<<<grid, block, 0, stream>>>(x, xs, W0, b0, W1, b1, W2, b2,
                                               out);
}

// Round 7
// 125.108 us; speedup vs baseline: 1.0146x; 1.0146x over previous
//
#include <hip/hip_runtime.h>

// B=16384, DIM=64, 8 coupling steps, H=8, D2=32.
// y = J^{-1} g applied analytically (triangular coupling blocks -> MLP JVPs);
// intermediate states recovered by inverting the flow from z = phi(x).
//
// R7 mapping: 16 lanes / element. L = tid&15; r = L&7 (row), hb = L>>3
// (t-net / s-net). Each lane owns dims {4r..4r+3} of every 32-vector (state
// replicated across hb groups) and computes FULL row r of each MLP layer —
// no cross-lane dot reductions. All cross-lane data movement is DPP (VALU
// pipe): quad_perm xor1/2/3, row_ror:4 (state xor4 — valid because both hb
// groups hold identical state), row_half_mirror (h-gather distances 4..7 via
// xor-reordered weight layouts), row_ror:8 (t/s exchange). Zero ds_swizzle.
// Weights packed f16x2 in LDS, column-major over r (16B stride, conflict-
// free); consumed by v_dot2_f32_f16 with fp32 accumulate. 39 KiB LDS ->
// 4 blocks/CU = 16 waves/CU (4/SIMD).

namespace {

typedef _Float16 f16;
typedef f16 f16x2 __attribute__((ext_vector_type(2)));

constexpr int NB    = 16384;
constexpr int NSTEP = 8;

constexpr int DPP_X1 = 0xB1;  // quad_perm {1,0,3,2}  = xor1
constexpr int DPP_X2 = 0x4E;  // quad_perm {2,3,0,1}  = xor2
constexpr int DPP_X3 = 0x1B;  // quad_perm {3,2,1,0}  = xor3
constexpr int DPP_R4 = 0x124; // row_ror:4  (lane+4 mod 16)
constexpr int DPP_R8 = 0x128; // row_ror:8  (= xor8 within 16-lane row)
constexpr int DPP_HM = 0x141; // row_half_mirror (= xor7 within 8)

__device__ __forceinline__ float frcp(float x) { return __builtin_amdgcn_rcpf(x); }

__device__ __forceinline__ float ftanh(float x) {
  float e = __expf(2.f * x);
  return 1.f - 2.f * frcp(e + 1.f);
}

__device__ __forceinline__ float fdot2(f16x2 a, f16x2 b, float c) {
  return __builtin_amdgcn_fdot2(a, b, c, false);
}
__device__ __forceinline__ f16x2 pk(float a, float b) {
  auto r = __builtin_amdgcn_cvt_pkrtz(a, b);
  return __builtin_bit_cast(f16x2, r);
}
template <int C>
__device__ __forceinline__ f16x2 dpph(f16x2 v) {
  int r = __builtin_amdgcn_update_dpp(0, __builtin_bit_cast(int, v), C, 0xF, 0xF, true);
  return __builtin_bit_cast(f16x2, r);
}
template <int C>
__device__ __forceinline__ float dppf(float v) {
  int r = __builtin_amdgcn_update_dpp(0, __float_as_int(v), C, 0xF, 0xF, true);
  return __int_as_float(r);
}

// Gather the full 32-dim vector as pairs, j-order: Vp[j] = chunk (r^j).
__device__ __forceinline__ void gather_v(const float v4[4], f16x2 Vp[8][2]) {
  Vp[0][0] = pk(v4[0], v4[1]);
  Vp[0][1] = pk(v4[2], v4[3]);
  Vp[4][0] = dpph<DPP_R4>(Vp[0][0]);
  Vp[4][1] = dpph<DPP_R4>(Vp[0][1]);
  Vp[1][0] = dpph<DPP_X1>(Vp[0][0]);
  Vp[1][1] = dpph<DPP_X1>(Vp[0][1]);
  Vp[2][0] = dpph<DPP_X2>(Vp[0][0]);
  Vp[2][1] = dpph<DPP_X2>(Vp[0][1]);
  Vp[3][0] = dpph<DPP_X3>(Vp[0][0]);
  Vp[3][1] = dpph<DPP_X3>(Vp[0][1]);
  Vp[5][0] = dpph<DPP_X1>(Vp[4][0]);
  Vp[5][1] = dpph<DPP_X1>(Vp[4][1]);
  Vp[6][0] = dpph<DPP_X2>(Vp[4][0]);
  Vp[6][1] = dpph<DPP_X2>(Vp[4][1]);
  Vp[7][0] = dpph<DPP_X3>(Vp[4][0]);
  Vp[7][1] = dpph<DPP_X3>(Vp[4][1]);
}

// Gather 8 per-row scalars (within the 8-lane hb-group) into 4 pairs:
// P[0]=(h[r],h[r^1]) P[1]=(h[r^2],h[r^3]) P[2]=(h[r^7],h[r^6]) P[3]=(h[r^5],h[r^4])
// (weights are staged in this exact xor order).
__device__ __forceinline__ void gather_h(float h, f16x2 P[4]) {
  float hx = dppf<DPP_X1>(h);
  P[0] = pk(h, hx);
  P[1] = dpph<DPP_X2>(P[0]);
  P[2] = dpph<DPP_HM>(P[0]);
  P[3] = dpph<DPP_HM>(P[1]);
}

// One MLP (net m), row r per lane; optional JVP sharing all weight loads.
template <bool JVP>
__device__ __forceinline__ void net_apply(
    const f16x2* __restrict__ sXW0, const f16x2* __restrict__ sXW1,
    const f16x2* __restrict__ sXW2, const f16x2* __restrict__ sBx01,
    const f16x2* __restrict__ sBx2, int m, int r, const float v4[4],
    const float* __restrict__ u4, float out4[4], float* __restrict__ jout4) {
  f16x2 Vp[8][2], Up[8][2];
  gather_v(v4, Vp);
  if constexpr (JVP) gather_v(u4, Up);

  const f16x2 bx = sBx01[m * 8 + r];
  float sv = (float)bx[0];
  float su = 0.f;
#pragma unroll
  for (int t = 0; t < 4; ++t) {
    float4 w = *(const float4*)(sXW0 + m * 128 + t * 32 + r * 4);
    f16x2 w0 = __builtin_bit_cast(f16x2, w.x);
    f16x2 w1 = __builtin_bit_cast(f16x2, w.y);
    f16x2 w2 = __builtin_bit_cast(f16x2, w.z);
    f16x2 w3 = __builtin_bit_cast(f16x2, w.w);
    sv = fdot2(w0, Vp[2 * t][0], sv);
    sv = fdot2(w1, Vp[2 * t][1], sv);
    sv = fdot2(w2, Vp[2 * t + 1][0], sv);
    sv = fdot2(w3, Vp[2 * t + 1][1], sv);
    if constexpr (JVP) {
      su = fdot2(w0, Up[2 * t][0], su);
      su = fdot2(w1, Up[2 * t][1], su);
      su = fdot2(w2, Up[2 * t + 1][0], su);
      su = fdot2(w3, Up[2 * t + 1][1], su);
    }
  }
  const float h1 = ftanh(sv);
  f16x2 H1[4], G1[4];
  gather_h(h1, H1);
  if constexpr (JVP) {
    const float g1 = (1.f - h1 * h1) * su;
    gather_h(g1, G1);
  }

  // layer 2 (row r)
  float4 wv = *(const float4*)(sXW1 + (m * 8 + r) * 4);
  f16x2 a0 = __builtin_bit_cast(f16x2, wv.x);
  f16x2 a1 = __builtin_bit_cast(f16x2, wv.y);
  f16x2 a2 = __builtin_bit_cast(f16x2, wv.z);
  f16x2 a3 = __builtin_bit_cast(f16x2, wv.w);
  float s2 = (float)bx[1];
  s2 = fdot2(a0, H1[0], s2);
  s2 = fdot2(a1, H1[1], s2);
  s2 = fdot2(a2, H1[2], s2);
  s2 = fdot2(a3, H1[3], s2);
  const float h2 = ftanh(s2);
  f16x2 H2[4], G2[4];
  gather_h(h2, H2);
  if constexpr (JVP) {
    float t2 = fdot2(a0, G1[0], 0.f);
    t2 = fdot2(a1, G1[1], t2);
    t2 = fdot2(a2, G1[2], t2);
    t2 = fdot2(a3, G1[3], t2);
    const float g2 = (1.f - h2 * h2) * t2;
    gather_h(g2, G2);
  }

  // layer 3: out dims d = r*4+c
  const float2 b2v = *(const float2*)(sBx2 + (m * 8 + r) * 2);
  const f16x2 bb0 = __builtin_bit_cast(f16x2, b2v.x);
  const f16x2 bb1 = __builtin_bit_cast(f16x2, b2v.y);
  const float bias3[4] = {(float)bb0[0], (float)bb0[1], (float)bb1[0],
                          (float)bb1[1]};
#pragma unroll
  for (int c = 0; c < 4; ++c) {
    float4 w = *(const float4*)(sXW2 + m * 128 + c * 32 + r * 4);
    f16x2 c0 = __builtin_bit_cast(f16x2, w.x);
    f16x2 c1 = __builtin_bit_cast(f16x2, w.y);
    f16x2 c2 = __builtin_bit_cast(f16x2, w.z);
    f16x2 c3 = __builtin_bit_cast(f16x2, w.w);
    float o = fdot2(c0, H2[0], bias3[c]);
    o = fdot2(c1, H2[1], o);
    o = fdot2(c2, H2[2], o);
    o = fdot2(c3, H2[3], o);
    out4[c] = o;
    if constexpr (JVP) {
      float jo = fdot2(c0, G2[0], 0.f);
      jo = fdot2(c1, G2[1], jo);
      jo = fdot2(c2, G2[2], jo);
      jo = fdot2(c3, G2[3], jo);
      jout4[c] = jo;
    }
  }
}

}  // namespace

// 256 threads = 16 elements/block, grid 1024. LDS 39936 B -> 4 blocks/CU,
// 16 waves/CU (4/SIMD).
__global__ __launch_bounds__(256, 4) void nf_policy_kernel(
    const float* __restrict__ x, const float* __restrict__ xs,
    const float* __restrict__ gW0, const float* __restrict__ gb0,
    const float* __restrict__ gW1, const float* __restrict__ gb1,
    const float* __restrict__ gW2, const float* __restrict__ gb2,
    float* __restrict__ out) {
  __shared__ __align__(16) f16x2 sXW0[4096];  // [32m][4t][8r][4p]
  __shared__ __align__(16) f16x2 sXW1[1024];  // [32m][8r][4j2]
  __shared__ __align__(16) f16x2 sXW2[4096];  // [32m][4c][8r][4j2]
  __shared__ __align__(16) f16x2 sBx01[256];  // [32m][8r] (b0,b1)
  __shared__ __align__(16) f16x2 sBx2[512];   // [32m][8r][2u]

  const int tid = threadIdx.x;
  const int X0[4] = {0, 2, 7, 5};
  const int X1[4] = {1, 3, 6, 4};
  // ---- stage weights (fp32 global -> xor-ordered f16x2 LDS) ----
  for (int i = tid; i < 4096; i += 256) {  // XW0
    const int p = i & 3, r = (i >> 2) & 7, t = (i >> 5) & 3, m = i >> 7;
    const int g = t * 4 + p, j = g >> 1, hp = g & 1;
    const float* b = gW0 + m * 256 + r * 32 + ((r ^ j) << 2) + hp * 2;
    sXW0[i] = pk(b[0], b[1]);
  }
  for (int i = tid; i < 1024; i += 256) {  // XW1
    const int j2 = i & 3, r = (i >> 2) & 7, m = i >> 5;
    const float* b = gW1 + m * 64 + r * 8;
    sXW1[i] = pk(b[r ^ X0[j2]], b[r ^ X1[j2]]);
  }
  for (int i = tid; i < 4096; i += 256) {  // XW2
    const int j2 = i & 3, r = (i >> 2) & 7, c = (i >> 5) & 3, m = i >> 7;
    const float* b = gW2 + m * 256 + (r * 4 + c) * 8;
    sXW2[i] = pk(b[r ^ X0[j2]], b[r ^ X1[j2]]);
  }
  for (int i = tid; i < 256; i += 256) {  // Bx01
    const int r = i & 7, m = i >> 3;
    sBx01[i] = pk(gb0[m * 8 + r], gb1[m * 8 + r]);
  }
  for (int i = tid; i < 512; i += 256) {  // Bx2
    const int u = i & 1, r = (i >> 1) & 7, m = i >> 4;
    const float* b = gb2 + m * 32 + r * 4 + 2 * u;
    sBx2[i] = pk(b[0], b[1]);
  }
  __syncthreads();

  const int e = blockIdx.x * 16 + (tid >> 4);
  const int L = tid & 15;
  const int r = L & 7;
  const bool hb = (L >> 3) & 1;  // 0: t-net, 1: s-net

  float lo4[4], up4[4], av4[4], bv4[4];
  {
    const float4 xl = *(const float4*)(x + (size_t)e * 64 + r * 4);
    const float4 xu = *(const float4*)(x + (size_t)e * 64 + 32 + r * 4);
    const float4 sl = *(const float4*)(xs + (size_t)e * 64 + r * 4);
    const float4 su = *(const float4*)(xs + (size_t)e * 64 + 32 + r * 4);
    lo4[0] = xl.x; lo4[1] = xl.y; lo4[2] = xl.z; lo4[3] = xl.w;
    up4[0] = xu.x; up4[1] = xu.y; up4[2] = xu.z; up4[3] = xu.w;
    av4[0] = -2.f * (xl.x - sl.x); av4[1] = -2.f * (xl.y - sl.y);
    av4[2] = -2.f * (xl.z - sl.z); av4[3] = -2.f * (xl.w - sl.w);
    bv4[0] = -2.f * (xu.x - su.x); bv4[1] = -2.f * (xu.y - su.y);
    bv4[2] = -2.f * (xu.z - su.z); bv4[3] = -2.f * (xu.w - su.w);
  }

  float o4[4], jo4[4], tt[4], ss[4], ut[4], us[4];

  // ---------------- forward: z = phi(x) ----------------
#pragma unroll 1
  for (int i = 0; i < NSTEP; ++i) {
    {
      const int m = i * 4 + (int)hb;  // t1 / s1 at lo
      net_apply<false>(sXW0, sXW1, sXW2, sBx01, sBx2, m, r, lo4, nullptr, o4,
                       nullptr);
#pragma unroll
      for (int c = 0; c < 4; ++c) {
        const float o = dppf<DPP_R8>(o4[c]);
        tt[c] = hb ? o : o4[c];
        ss[c] = hb ? o4[c] : o;
      }
#pragma unroll
      for (int c = 0; c < 4; ++c) up4[c] = fmaf(up4[c], __expf(ss[c]), tt[c]);
    }
    {
      const int m = i * 4 + 2 + (int)hb;  // t2 / s2 at up
      net_apply<false>(sXW0, sXW1, sXW2, sBx01, sBx2, m, r, up4, nullptr, o4,
                       nullptr);
#pragma unroll
      for (int c = 0; c < 4; ++c) {
        const float o = dppf<DPP_R8>(o4[c]);
        tt[c] = hb ? o : o4[c];
        ss[c] = hb ? o4[c] : o;
      }
#pragma unroll
      for (int c = 0; c < 4; ++c) lo4[c] = fmaf(lo4[c], __expf(ss[c]), tt[c]);
    }
  }

  // ------------- backward: y = J^{-1} g, inverting the flow -------------
#pragma unroll 1
  for (int i = NSTEP - 1; i >= 0; --i) {
    {  // T2^{-1}: eval t2/s2 at up', JVP at bv
      const int m = i * 4 + 2 + (int)hb;
      net_apply<true>(sXW0, sXW1, sXW2, sBx01, sBx2, m, r, up4, bv4, o4, jo4);
#pragma unroll
      for (int c = 0; c < 4; ++c) {
        const float o = dppf<DPP_R8>(o4[c]);
        tt[c] = hb ? o : o4[c];
        ss[c] = hb ? o4[c] : o;
        const float ju = dppf<DPP_R8>(jo4[c]);
        ut[c] = hb ? ju : jo4[c];
        us[c] = hb ? jo4[c] : ju;
      }
#pragma unroll
      for (int c = 0; c < 4; ++c) {
        const float esi = __expf(-ss[c]);
        const float d = lo4[c] - tt[c];
        lo4[c] = d * esi;                                   // pre-step lo
        av4[c] = (av4[c] - ut[c] - d * us[c]) * esi;        // J_T2^{-T}-free form
      }
    }
    {  // T1^{-1}: eval t1/s1 at lo (pre-step), JVP at av (updated)
      const int m = i * 4 + (int)hb;
      net_apply<true>(sXW0, sXW1, sXW2, sBx01, sBx2, m, r, lo4, av4, o4, jo4);
#pragma unroll
      for (int c = 0; c < 4; ++c) {
        const float o = dppf<DPP_R8>(o4[c]);
        tt[c] = hb ? o : o4[c];
        ss[c] = hb ? o4[c] : o;
        const float ju = dppf<DPP_R8>(jo4[c]);
        ut[c] = hb ? ju : jo4[c];
        us[c] = hb ? jo4[c] : ju;
      }
#pragma unroll
      for (int c = 0; c < 4; ++c) {
        const float esi = __expf(-ss[c]);
        const float d = up4[c] - tt[c];
        up4[c] = d * esi;                                   // pre-step up
        bv4[c] = (bv4[c] - ut[c] - d * us[c]) * esi;
      }
    }
  }

  if (!hb) {
    float4 v;
    v.x = av4[0]; v.y = av4[1]; v.z = av4[2]; v.w = av4[3];
    *(float4*)(out + (size_t)e * 64 + r * 4) = v;
    v.x = bv4[0]; v.y = bv4[1]; v.z = bv4[2]; v.w = bv4[3];
    *(float4*)(out + (size_t)e * 64 + 32 + r * 4) = v;
  }
}

extern "C" void kernel_launch(void* const* d_in, const int* in_sizes, int n_in,
                              void* d_out, int out_size, void* d_ws,
                              size_t ws_size, hipStream_t stream) {
  const float* x  = (const float*)d_in[0];
  const float* xs = (const float*)d_in[1];
  const float* W0 = (const float*)d_in[2];
  const float* b0 = (const float*)d_in[3];
  const float* W1 = (const float*)d_in[4];
  const float* b1 = (const float*)d_in[5];
  const float* W2 = (const float*)d_in[6];
  const float* b2 = (const float*)d_in[7];
  float* out = (float*)d_out;

  dim3 grid(NB / 16);  // 1024 blocks, 16 elements each
  dim3 block(256);
  nf_policy_kernel<<<grid, block, 0, stream>>>(x, xs, W0, b0, W1, b1, W2, b2,
                                               out);
}